// Round 8
// baseline (289.383 us; speedup 1.0000x reference)
//
#include <hip/hip_runtime.h>
#include <hip/hip_bf16.h>

typedef __hip_bfloat16 bf16;

#define DEPS 1e-16f
#define CAP 32
#define OVF_MAX 131072
#define CSH 4                    // cnt stride shift: 1 counter per 64B line

__device__ __forceinline__ float bfu_lo(unsigned u) { return __uint_as_float(u << 16); }
__device__ __forceinline__ float bfu_hi(unsigned u) { return __uint_as_float(u & 0xffff0000u); }

// bucket entry: (s << 15) | q, wt = q/8192 - 1.1, q in [0,32767]
__device__ __forceinline__ float dec_wt(unsigned u) {
    return (float)(u & 32767u) * (1.f / 8192.f) - 1.1f;
}

// Heterogeneous dispatch, stripe 15:4 gemm:hist. Session rules: gemm pairs
// ONLY with the atomic pass (R2 +, R3 -); cooperative grid.sync is a 2.2x
// regression (R4); hist+scatter fusion needs >=8-deep ILP (R1 -, R6 +);
// hand-ILP in the high-occupancy agg kernels is neutral/negative (R7).
// THIS ROUND's single variable: cnt padded to 1 counter / 64B line (CSH=4)
// to break potential per-cache-line atomic-RMW serialization (16 counters
// per line x ~16 hits each = ~256 serialized RMWs/line in the dense layout).
__global__ __launch_bounds__(256) void f_gemm_hs(
    const float* __restrict__ x, const float* __restrict__ W1,
    const float* __restrict__ a_src, const float* __restrict__ a_dst,
    bf16* __restrict__ h1, float* __restrict__ asrc, float* __restrict__ adst,
    const int* __restrict__ srcv, const int* __restrict__ dstv,
    const float* __restrict__ ew,
    int* __restrict__ cnt, unsigned* __restrict__ bkt,
    uint2* __restrict__ ovf, int* __restrict__ ovfn,
    int N, int E, int T, int gG, int gH)
{
    __shared__ __align__(16) float xl[32 * 128];   // 16 KB
    int bid = blockIdx.x;
    int r = bid % 19, chunk = bid / 19;
    int tid = threadIdx.x;

    if (r < 4) {                                   // ---- hist role (4/19) ----
        int hb = chunk * 4 + r;
        if (hb >= gH) return;
        int e0 = hb * 2048 + tid;                  // 8 edges/thread, stride 256
        int d_[8], pos_[8], s_[8];
        float w_[8];
        // phase A: coalesced loads + independent atomics (pipelined)
        #pragma unroll
        for (int i = 0; i < 8; ++i) {
            int e = e0 + i * 256;
            d_[i] = -1; pos_[i] = 0; s_[i] = 0; w_[i] = 1.f;
            if (e < T) {
                if (e < E) {
                    d_[i] = dstv[e];
                    s_[i] = srcv[e];
                    w_[i] = ew[e];
                    pos_[i] = atomicAdd(&cnt[(size_t)d_[i] << CSH], 1);
                } else {                           // self-loop: slot 0, no atomic
                    d_[i] = e - E;
                    s_[i] = d_[i];
                    pos_[i] = -1;                  // -> slot 0
                    w_[i] = -1.f;                  // marker: wt = 0
                }
            }
        }
        // phase B: independent scattered stores
        #pragma unroll
        for (int i = 0; i < 8; ++i) {
            if (d_[i] < 0) continue;
            float wt = (w_[i] < 0.f) ? 0.f : (1.f - 1.f / w_[i]);
            unsigned q = (unsigned)((wt + 1.1f) * 8192.f + 0.5f);
            unsigned entry = ((unsigned)s_[i] << 15) | q;
            int slot = 1 + pos_[i];
            if (slot < CAP) {
                bkt[(size_t)d_[i] * CAP + slot] = entry;
            } else {
                int o = atomicAdd(ovfn, 1);        // ~tens of edges device-wide
                if (o < OVF_MAX) { uint2 v; v.x = (unsigned)d_[i]; v.y = entry; ovf[o] = v; }
            }
        }
        return;
    }
    // ---- gemm role (15/19) ----
    int gb = chunk * 15 + (r - 4);
    if (gb >= gG) return;
    int n0 = gb * 32;
    for (int i = tid; i < 1024; i += 256) {
        int n = n0 + (i >> 5);
        float4 v = {0.f, 0.f, 0.f, 0.f};
        if (n < N) v = ((const float4*)x)[(size_t)n * 32 + (i & 31)];
        ((float4*)xl)[i] = v;
    }
    __syncthreads();
    int w = tid >> 6, c = tid & 63;
    float sa = a_src[c], da = a_dst[c];
    float acc[8] = {0.f, 0.f, 0.f, 0.f, 0.f, 0.f, 0.f, 0.f};
    const float* Wc = W1 + c;                      // column pointer, stride 64
    for (int k4 = 0; k4 < 32; ++k4) {
        float w0 = Wc[(4 * k4 + 0) * 64];
        float w1 = Wc[(4 * k4 + 1) * 64];
        float w2 = Wc[(4 * k4 + 2) * 64];
        float w3 = Wc[(4 * k4 + 3) * 64];
        #pragma unroll
        for (int i = 0; i < 8; ++i) {
            float4 xv = ((const float4*)(xl + (w * 8 + i) * 128))[k4];
            acc[i] = fmaf(xv.x, w0, fmaf(xv.y, w1,
                     fmaf(xv.z, w2, fmaf(xv.w, w3, acc[i]))));
        }
    }
    #pragma unroll
    for (int i = 0; i < 8; ++i) {
        int n = n0 + w * 8 + i;
        float a = acc[i];
        float ps = a * sa, pd = a * da;
        #pragma unroll
        for (int o = 32; o; o >>= 1) {
            ps += __shfl_xor(ps, o);
            pd += __shfl_xor(pd, o);
        }
        if (n < N) {
            h1[(size_t)n * 64 + c] = __float2bfloat16(a);
            if (c == 0) { asrc[n] = ps; adst[n] = pd; }
        }
    }
}

// fused layer-1 aggregate + slim layer-2 epilogue. One wave per dst.
// lenf = cnt[d] + 1 (self-loop occupies slot 0; cnt counts real edges).
// (R6-exact body; R7's hand-pipelining was neutral/negative.)
__global__ __launch_bounds__(256) void f_agg1(
    const int* __restrict__ cnt, const unsigned* __restrict__ bkt,
    const uint2* __restrict__ ovf, const int* __restrict__ ovfn,
    const float* __restrict__ asrc, const float* __restrict__ adst,
    const bf16* __restrict__ h1,
    const float* __restrict__ b1, const float* __restrict__ W2,
    const float* __restrict__ a2s, const float* __restrict__ a2d,
    float* __restrict__ h2p, float* __restrict__ ad2, int N)
{
    __shared__ __align__(16) float WxT[16][68];  // 4.25 KB
    __shared__ __align__(16) float b1l[64];
    __shared__ float2 eb[4][64];                 // wave-private slices
    int tid = threadIdx.x;
    if (tid < 64) {
        float us = 0.f, ud = 0.f;
        #pragma unroll
        for (int c = 0; c < 7; ++c) {
            float wv = W2[tid * 7 + c];
            WxT[c][tid] = wv;
            us = fmaf(wv, a2s[c], us);
            ud = fmaf(wv, a2d[c], ud);
        }
        WxT[7][tid] = us;
        WxT[8][tid] = ud;
        #pragma unroll
        for (int r = 9; r < 16; ++r) WxT[r][tid] = 0.f;
        b1l[tid] = b1[tid];
    }
    __syncthreads();
    int d = blockIdx.x * 4 + (tid >> 6);
    int lane = tid & 63;
    if (d >= N) return;
    int lenf = cnt[(size_t)d << CSH] + 1;
    int nc = min(lenf, CAP);
    size_t r0 = (size_t)d * CAP;
    float adv = adst[d];
    int g8 = lane >> 3, l8 = lane & 7;
    float2* ebw = eb[tid >> 6];
    float acc[8] = {0.f, 0.f, 0.f, 0.f, 0.f, 0.f, 0.f, 0.f};
    float sm = 0.f;
    {
        float ea = 0.f; unsigned s = 0;
        if (lane < nc) {
            unsigned u = bkt[r0 + lane];
            s = u >> 15;
            float a = asrc[s] + adv;
            a = (a > 0.f) ? a : 0.2f * a;
            ea = __expf(a + dec_wt(u));
            sm += ea;
        }
        ebw[lane] = make_float2(ea, __uint_as_float(s));
        for (int j = 0; j < nc; j += 8) {
            float2 eq = ebw[j + g8];             // 8 addrs, 8-lane broadcast
            float e = eq.x;                      // padded slots have e==0
            unsigned sj = __float_as_uint(eq.y);
            uint4 hv = *(const uint4*)&h1[(size_t)sj * 64 + (l8 << 3)];
            acc[0] = fmaf(e, bfu_lo(hv.x), acc[0]);
            acc[1] = fmaf(e, bfu_hi(hv.x), acc[1]);
            acc[2] = fmaf(e, bfu_lo(hv.y), acc[2]);
            acc[3] = fmaf(e, bfu_hi(hv.y), acc[3]);
            acc[4] = fmaf(e, bfu_lo(hv.z), acc[4]);
            acc[5] = fmaf(e, bfu_hi(hv.z), acc[5]);
            acc[6] = fmaf(e, bfu_lo(hv.w), acc[6]);
            acc[7] = fmaf(e, bfu_hi(hv.w), acc[7]);
        }
    }
    if (lenf > CAP) {                            // rare overflow path
        int no = min(*ovfn, OVF_MAX);
        for (int i = g8; i < no; i += 8) {       // entry i -> group i&7
            uint2 ov = ovf[i];
            if ((int)ov.x == d) {
                unsigned u = ov.y;
                unsigned s = u >> 15;
                float a = asrc[s] + adv;
                a = (a > 0.f) ? a : 0.2f * a;
                float ea = __expf(a + dec_wt(u));
                if (l8 == 0) sm += ea;           // count edge exactly once
                uint4 hv = *(const uint4*)&h1[(size_t)s * 64 + (l8 << 3)];
                acc[0] = fmaf(ea, bfu_lo(hv.x), acc[0]);
                acc[1] = fmaf(ea, bfu_hi(hv.x), acc[1]);
                acc[2] = fmaf(ea, bfu_lo(hv.y), acc[2]);
                acc[3] = fmaf(ea, bfu_hi(hv.y), acc[3]);
                acc[4] = fmaf(ea, bfu_lo(hv.z), acc[4]);
                acc[5] = fmaf(ea, bfu_hi(hv.z), acc[5]);
                acc[6] = fmaf(ea, bfu_lo(hv.w), acc[6]);
                acc[7] = fmaf(ea, bfu_hi(hv.w), acc[7]);
            }
        }
    }
    #pragma unroll
    for (int o = 32; o; o >>= 1) sm += __shfl_xor(sm, o);
    #pragma unroll
    for (int k = 0; k < 8; ++k) {
        acc[k] += __shfl_xor(acc[k], 8);
        acc[k] += __shfl_xor(acc[k], 16);
        acc[k] += __shfl_xor(acc[k], 32);
    }
    float inv = 1.f / (sm + DEPS);
    int c0 = l8 << 3;
    float4 bA = *(const float4*)&b1l[c0];
    float4 bB = *(const float4*)&b1l[c0 + 4];
    float v0 = fmaxf(fmaf(acc[0], inv, bA.x), 0.f);
    float v1 = fmaxf(fmaf(acc[1], inv, bA.y), 0.f);
    float v2 = fmaxf(fmaf(acc[2], inv, bA.z), 0.f);
    float v3 = fmaxf(fmaf(acc[3], inv, bA.w), 0.f);
    float v4 = fmaxf(fmaf(acc[4], inv, bB.x), 0.f);
    float v5 = fmaxf(fmaf(acc[5], inv, bB.y), 0.f);
    float v6 = fmaxf(fmaf(acc[6], inv, bB.z), 0.f);
    float v7 = fmaxf(fmaf(acc[7], inv, bB.w), 0.f);
    float4 wA0 = *(const float4*)&WxT[g8][c0];
    float4 wA1 = *(const float4*)&WxT[g8][c0 + 4];
    float4 wB0 = *(const float4*)&WxT[g8 + 8][c0];
    float4 wB1 = *(const float4*)&WxT[g8 + 8][c0 + 4];
    float rA = fmaf(v0, wA0.x, fmaf(v1, wA0.y, fmaf(v2, wA0.z, fmaf(v3, wA0.w,
               fmaf(v4, wA1.x, fmaf(v5, wA1.y, fmaf(v6, wA1.z, v7 * wA1.w)))))));
    float rB = fmaf(v0, wB0.x, fmaf(v1, wB0.y, fmaf(v2, wB0.z, fmaf(v3, wB0.w,
               fmaf(v4, wB1.x, fmaf(v5, wB1.y, fmaf(v6, wB1.z, v7 * wB1.w)))))));
    rA += __shfl_xor(rA, 1); rA += __shfl_xor(rA, 2); rA += __shfl_xor(rA, 4);
    rB += __shfl_xor(rB, 1); rB += __shfl_xor(rB, 2); rB += __shfl_xor(rB, 4);
    if (l8 == 0) {
        h2p[(size_t)d * 8 + g8] = rA;            // slots 0..6 = h2, 7 = as2
        if (g8 == 0) ad2[d] = rB;                // output 8 = ad2
    }
}

// fused layer-2 aggregate + bias. 8 lanes per row, 8 rows per wave.
// (R6-exact body.)
__global__ __launch_bounds__(256) void f_agg2(
    const int* __restrict__ cnt, const unsigned* __restrict__ bkt,
    const uint2* __restrict__ ovf, const int* __restrict__ ovfn,
    const float* __restrict__ h2p, const float* __restrict__ ad2,
    const float* __restrict__ b2, float* __restrict__ out, int N)
{
    __shared__ float b2l[7];
    if (threadIdx.x < 7) b2l[threadIdx.x] = b2[threadIdx.x];
    __syncthreads();
    int lane = threadIdx.x & 63;
    int wv = threadIdx.x >> 6;
    int grp = lane >> 3, l8 = lane & 7;
    int d = blockIdx.x * 32 + wv * 8 + grp;
    bool valid = d < N;
    int lenf = 0; float adv = 0.f;
    if (valid) { lenf = cnt[(size_t)d << CSH] + 1; adv = ad2[d]; }
    int nc = min(lenf, CAP);
    size_t r0 = (size_t)d * CAP;
    float sm = 0.f;
    float a0 = 0.f, a1 = 0.f, a2 = 0.f, a3 = 0.f, a4 = 0.f, a5 = 0.f, a6 = 0.f;
    for (int p = l8; p < nc; p += 8) {
        unsigned u = bkt[r0 + p];
        int s = (int)(u >> 15);
        const float* hr = &h2p[(size_t)s * 8];
        float4 A = *(const float4*)hr;
        float4 B = *(const float4*)(hr + 4);
        float a = B.w + adv;
        a = (a > 0.f) ? a : 0.2f * a;
        float ea = __expf(a + dec_wt(u));
        sm += ea;
        a0 = fmaf(ea, A.x, a0); a1 = fmaf(ea, A.y, a1);
        a2 = fmaf(ea, A.z, a2); a3 = fmaf(ea, A.w, a3);
        a4 = fmaf(ea, B.x, a4); a5 = fmaf(ea, B.y, a5);
        a6 = fmaf(ea, B.z, a6);
    }
    if (lenf > CAP) {                            // rare overflow path
        int no = min(*ovfn, OVF_MAX);
        for (int i = l8; i < no; i += 8) {
            uint2 ov = ovf[i];
            if ((int)ov.x == d) {
                unsigned u = ov.y;
                int s = (int)(u >> 15);
                const float* hr = &h2p[(size_t)s * 8];
                float4 A = *(const float4*)hr;
                float4 B = *(const float4*)(hr + 4);
                float a = B.w + adv;
                a = (a > 0.f) ? a : 0.2f * a;
                float ea = __expf(a + dec_wt(u));
                sm += ea;
                a0 = fmaf(ea, A.x, a0); a1 = fmaf(ea, A.y, a1);
                a2 = fmaf(ea, A.z, a2); a3 = fmaf(ea, A.w, a3);
                a4 = fmaf(ea, B.x, a4); a5 = fmaf(ea, B.y, a5);
                a6 = fmaf(ea, B.z, a6);
            }
        }
    }
    #pragma unroll
    for (int o = 4; o; o >>= 1) {
        sm += __shfl_xor(sm, o);
        a0 += __shfl_xor(a0, o); a1 += __shfl_xor(a1, o);
        a2 += __shfl_xor(a2, o); a3 += __shfl_xor(a3, o);
        a4 += __shfl_xor(a4, o); a5 += __shfl_xor(a5, o);
        a6 += __shfl_xor(a6, o);
    }
    if (valid && l8 < 7) {
        float inv = 1.f / (sm + DEPS);
        float val = (l8 < 4) ? ((l8 < 2) ? (l8 ? a1 : a0) : ((l8 == 2) ? a2 : a3))
                             : ((l8 < 6) ? ((l8 == 4) ? a4 : a5) : a6);
        out[(size_t)d * 7 + l8] = fmaf(val, inv, b2l[l8]);
    }
}

// ============================== HOST ======================================

extern "C" void kernel_launch(void* const* d_in, const int* in_sizes, int n_in,
                              void* d_out, int out_size, void* d_ws, size_t ws_size,
                              hipStream_t stream) {
    const float* x   = (const float*)d_in[0];
    const int*   ei  = (const int*)d_in[1];
    const float* ew  = (const float*)d_in[2];
    const float* W1  = (const float*)d_in[3];
    const float* as1 = (const float*)d_in[4];
    const float* ad1 = (const float*)d_in[5];
    const float* b1  = (const float*)d_in[6];
    const float* W2  = (const float*)d_in[7];
    const float* a2s = (const float*)d_in[8];
    const float* a2d = (const float*)d_in[9];
    const float* b2  = (const float*)d_in[10];

    int N = in_sizes[0] / 128;
    int E = in_sizes[1] / 2;
    int T = E + N;
    const int* srcv = ei;
    const int* dstv = ei + E;
    float* out = (float*)d_out;

    // workspace (256B aligned): ~37.5 MB (cnt now padded: 1 counter/64B line).
    size_t A = 0;
    auto take = [&](size_t b) { size_t o = A; A = (A + b + 255) & ~(size_t)255; return o; };
    size_t o_h1   = take((size_t)N * 64 * 2);       // 12.8 MB
    size_t o_bkt  = take((size_t)N * CAP * 4);      // 12.8 MB
    size_t o_h2p  = take((size_t)N * 8 * 4);        //  3.2 MB padded (+as2)
    size_t o_ovf  = take((size_t)OVF_MAX * 8);      //  1.0 MB
    size_t o_cnt  = take((size_t)N * 64);           //  6.4 MB (stride-16 ints)
    size_t o_ovfn = take(256);                      //  (contiguous after cnt)
    size_t o_asrc = take((size_t)N * 4);
    size_t o_adst = take((size_t)N * 4);
    size_t o_ad2  = take((size_t)N * 4);

    char* base = (char*)d_ws;
    bf16*     h1    = (bf16*)(base + o_h1);
    unsigned* bkt   = (unsigned*)(base + o_bkt);
    float*    h2p   = (float*)(base + o_h2p);
    uint2*    ovf   = (uint2*)(base + o_ovf);
    int*      cnt   = (int*)(base + o_cnt);
    int*      ovfn  = (int*)(base + o_ovfn);
    float*    asrc  = (float*)(base + o_asrc);
    float*    adst  = (float*)(base + o_adst);
    float*    ad2   = (float*)(base + o_ad2);

    int gG = (N + 31) / 32;                  // gemm-role blocks (~3125)
    int gH = (T + 2047) / 2048;              // fused hist+scat blocks (~831)
    int chunks = max((gG + 14) / 15, (gH + 3) / 4);
    int gridGH = chunks * 19;                // 15:4 stripe for co-residency

    hipMemsetAsync(cnt, 0, (size_t)N * 64 + 256, stream);  // cnt + ovfn
    f_gemm_hs<<<gridGH, 256, 0, stream>>>(x, W1, as1, ad1, h1, asrc, adst,
                                          srcv, dstv, ew, cnt, bkt, ovf, ovfn,
                                          N, E, T, gG, gH);
    f_agg1 <<<(N + 3) / 4, 256, 0, stream>>>(cnt, bkt, ovf, ovfn, asrc, adst, h1,
                                             b1, W2, a2s, a2d, h2p, ad2, N);
    f_agg2 <<<(N + 31) / 32, 256, 0, stream>>>(cnt, bkt, ovf, ovfn, h2p, ad2, b2, out, N);
}

// Round 9
// 273.654 us; speedup vs baseline: 1.0575x; 1.0575x over previous
//
#include <hip/hip_runtime.h>
#include <hip/hip_bf16.h>

typedef __hip_bfloat16 bf16;

#define DEPS 1e-16f
#define CAP 32
#define OVF_MAX 131072

__device__ __forceinline__ float bfu_lo(unsigned u) { return __uint_as_float(u << 16); }
__device__ __forceinline__ float bfu_hi(unsigned u) { return __uint_as_float(u & 0xffff0000u); }

// bucket entry: (s << 15) | q, wt = q/8192 - 1.1, q in [0,32767]
__device__ __forceinline__ float dec_wt(unsigned u) {
    return (float)(u & 32767u) * (1.f / 8192.f) - 1.1f;
}

// Heterogeneous dispatch, stripe 15:4 gemm:hist. Session rules: gemm pairs
// ONLY with the atomic pass (R2 +, R3 -); cooperative grid.sync is a 2.2x
// regression (R4); hist+scatter fusion needs >=8-deep ILP (R1 -, R6 +);
// hand-ILP in high-occupancy agg kernels is neutral/negative (R7);
// DENSE atomic counters beat 64B-padded ones (R8).
// THIS ROUND: self-loops removed from the pipeline entirely -- handled
// analytically in the agg kernels (term = exp(leaky(asrc[d]+adst[d])),
// feature row = own row). Hist role covers only the E real edges; every
// bucket slot 0..31 now holds real edges (capacity 31 -> 32).
__global__ __launch_bounds__(256) void f_gemm_hs(
    const float* __restrict__ x, const float* __restrict__ W1,
    const float* __restrict__ a_src, const float* __restrict__ a_dst,
    bf16* __restrict__ h1, float* __restrict__ asrc, float* __restrict__ adst,
    const int* __restrict__ srcv, const int* __restrict__ dstv,
    const float* __restrict__ ew,
    int* __restrict__ cnt, unsigned* __restrict__ bkt,
    uint2* __restrict__ ovf, int* __restrict__ ovfn,
    int N, int E, int gG, int gH)
{
    __shared__ __align__(16) float xl[32 * 128];   // 16 KB
    int bid = blockIdx.x;
    int r = bid % 19, chunk = bid / 19;
    int tid = threadIdx.x;

    if (r < 4) {                                   // ---- hist role (4/19) ----
        int hb = chunk * 4 + r;
        if (hb >= gH) return;
        int e0 = hb * 2048 + tid;                  // 8 edges/thread, stride 256
        int d_[8], pos_[8], s_[8];
        float w_[8];
        // phase A: coalesced loads + independent atomics (pipelined)
        #pragma unroll
        for (int i = 0; i < 8; ++i) {
            int e = e0 + i * 256;
            d_[i] = -1; pos_[i] = 0; s_[i] = 0; w_[i] = 1.f;
            if (e < E) {
                d_[i] = dstv[e];
                s_[i] = srcv[e];
                w_[i] = ew[e];
                pos_[i] = atomicAdd(&cnt[d_[i]], 1);
            }
        }
        // phase B: independent scattered stores
        #pragma unroll
        for (int i = 0; i < 8; ++i) {
            if (d_[i] < 0) continue;
            float wt = 1.f - 1.f / w_[i];
            unsigned q = (unsigned)((wt + 1.1f) * 8192.f + 0.5f);
            unsigned entry = ((unsigned)s_[i] << 15) | q;
            int slot = pos_[i];
            if (slot < CAP) {
                bkt[(size_t)d_[i] * CAP + slot] = entry;
            } else {
                int o = atomicAdd(ovfn, 1);        // ~tens of edges device-wide
                if (o < OVF_MAX) { uint2 v; v.x = (unsigned)d_[i]; v.y = entry; ovf[o] = v; }
            }
        }
        return;
    }
    // ---- gemm role (15/19) ----
    int gb = chunk * 15 + (r - 4);
    if (gb >= gG) return;
    int n0 = gb * 32;
    for (int i = tid; i < 1024; i += 256) {
        int n = n0 + (i >> 5);
        float4 v = {0.f, 0.f, 0.f, 0.f};
        if (n < N) v = ((const float4*)x)[(size_t)n * 32 + (i & 31)];
        ((float4*)xl)[i] = v;
    }
    __syncthreads();
    int w = tid >> 6, c = tid & 63;
    float sa = a_src[c], da = a_dst[c];
    float acc[8] = {0.f, 0.f, 0.f, 0.f, 0.f, 0.f, 0.f, 0.f};
    const float* Wc = W1 + c;                      // column pointer, stride 64
    for (int k4 = 0; k4 < 32; ++k4) {
        float w0 = Wc[(4 * k4 + 0) * 64];
        float w1 = Wc[(4 * k4 + 1) * 64];
        float w2 = Wc[(4 * k4 + 2) * 64];
        float w3 = Wc[(4 * k4 + 3) * 64];
        #pragma unroll
        for (int i = 0; i < 8; ++i) {
            float4 xv = ((const float4*)(xl + (w * 8 + i) * 128))[k4];
            acc[i] = fmaf(xv.x, w0, fmaf(xv.y, w1,
                     fmaf(xv.z, w2, fmaf(xv.w, w3, acc[i]))));
        }
    }
    #pragma unroll
    for (int i = 0; i < 8; ++i) {
        int n = n0 + w * 8 + i;
        float a = acc[i];
        float ps = a * sa, pd = a * da;
        #pragma unroll
        for (int o = 32; o; o >>= 1) {
            ps += __shfl_xor(ps, o);
            pd += __shfl_xor(pd, o);
        }
        if (n < N) {
            h1[(size_t)n * 64 + c] = __float2bfloat16(a);
            if (c == 0) { asrc[n] = ps; adst[n] = pd; }
        }
    }
}

// fused layer-1 aggregate + slim layer-2 epilogue. One wave per dst.
// cnt[d] = real in-degree; self-loop handled ANALYTICALLY: term
// ea_self = exp(leaky(asrc[d]+adst[d])), features = h1[d] row (group 0
// adds it pre-reduction; lane 0 adds ea_self to sm).
__global__ __launch_bounds__(256) void f_agg1(
    const int* __restrict__ cnt, const unsigned* __restrict__ bkt,
    const uint2* __restrict__ ovf, const int* __restrict__ ovfn,
    const float* __restrict__ asrc, const float* __restrict__ adst,
    const bf16* __restrict__ h1,
    const float* __restrict__ b1, const float* __restrict__ W2,
    const float* __restrict__ a2s, const float* __restrict__ a2d,
    float* __restrict__ h2p, float* __restrict__ ad2, int N)
{
    __shared__ __align__(16) float WxT[16][68];  // 4.25 KB
    __shared__ __align__(16) float b1l[64];
    __shared__ float2 eb[4][64];                 // wave-private slices
    int tid = threadIdx.x;
    if (tid < 64) {
        float us = 0.f, ud = 0.f;
        #pragma unroll
        for (int c = 0; c < 7; ++c) {
            float wv = W2[tid * 7 + c];
            WxT[c][tid] = wv;
            us = fmaf(wv, a2s[c], us);
            ud = fmaf(wv, a2d[c], ud);
        }
        WxT[7][tid] = us;
        WxT[8][tid] = ud;
        #pragma unroll
        for (int r = 9; r < 16; ++r) WxT[r][tid] = 0.f;
        b1l[tid] = b1[tid];
    }
    __syncthreads();
    int d = blockIdx.x * 4 + (tid >> 6);
    int lane = tid & 63;
    if (d >= N) return;
    int lenf = cnt[d];                           // real edges only
    int nc = min(lenf, CAP);
    size_t r0 = (size_t)d * CAP;
    float adv = adst[d];
    int g8 = lane >> 3, l8 = lane & 7;
    float2* ebw = eb[tid >> 6];
    float acc[8] = {0.f, 0.f, 0.f, 0.f, 0.f, 0.f, 0.f, 0.f};
    float sm = 0.f;
    // analytic self-loop term
    {
        float a_self = asrc[d] + adv;
        a_self = (a_self > 0.f) ? a_self : 0.2f * a_self;
        float eas = __expf(a_self);
        if (lane == 0) sm += eas;                // counted once in wave-reduce
        if (g8 == 0) {                           // group 0 only: once per channel
            uint4 hv = *(const uint4*)&h1[(size_t)d * 64 + (l8 << 3)];
            acc[0] = fmaf(eas, bfu_lo(hv.x), acc[0]);
            acc[1] = fmaf(eas, bfu_hi(hv.x), acc[1]);
            acc[2] = fmaf(eas, bfu_lo(hv.y), acc[2]);
            acc[3] = fmaf(eas, bfu_hi(hv.y), acc[3]);
            acc[4] = fmaf(eas, bfu_lo(hv.z), acc[4]);
            acc[5] = fmaf(eas, bfu_hi(hv.z), acc[5]);
            acc[6] = fmaf(eas, bfu_lo(hv.w), acc[6]);
            acc[7] = fmaf(eas, bfu_hi(hv.w), acc[7]);
        }
    }
    {
        float ea = 0.f; unsigned s = 0;
        if (lane < nc) {
            unsigned u = bkt[r0 + lane];
            s = u >> 15;
            float a = asrc[s] + adv;
            a = (a > 0.f) ? a : 0.2f * a;
            ea = __expf(a + dec_wt(u));
            sm += ea;
        }
        ebw[lane] = make_float2(ea, __uint_as_float(s));
        for (int j = 0; j < nc; j += 8) {
            float2 eq = ebw[j + g8];             // 8 addrs, 8-lane broadcast
            float e = eq.x;                      // padded slots have e==0
            unsigned sj = __float_as_uint(eq.y);
            uint4 hv = *(const uint4*)&h1[(size_t)sj * 64 + (l8 << 3)];
            acc[0] = fmaf(e, bfu_lo(hv.x), acc[0]);
            acc[1] = fmaf(e, bfu_hi(hv.x), acc[1]);
            acc[2] = fmaf(e, bfu_lo(hv.y), acc[2]);
            acc[3] = fmaf(e, bfu_hi(hv.y), acc[3]);
            acc[4] = fmaf(e, bfu_lo(hv.z), acc[4]);
            acc[5] = fmaf(e, bfu_hi(hv.z), acc[5]);
            acc[6] = fmaf(e, bfu_lo(hv.w), acc[6]);
            acc[7] = fmaf(e, bfu_hi(hv.w), acc[7]);
        }
    }
    if (lenf > CAP) {                            // rare overflow path
        int no = min(*ovfn, OVF_MAX);
        for (int i = g8; i < no; i += 8) {       // entry i -> group i&7
            uint2 ov = ovf[i];
            if ((int)ov.x == d) {
                unsigned u = ov.y;
                unsigned s = u >> 15;
                float a = asrc[s] + adv;
                a = (a > 0.f) ? a : 0.2f * a;
                float ea = __expf(a + dec_wt(u));
                if (l8 == 0) sm += ea;           // count edge exactly once
                uint4 hv = *(const uint4*)&h1[(size_t)s * 64 + (l8 << 3)];
                acc[0] = fmaf(ea, bfu_lo(hv.x), acc[0]);
                acc[1] = fmaf(ea, bfu_hi(hv.x), acc[1]);
                acc[2] = fmaf(ea, bfu_lo(hv.y), acc[2]);
                acc[3] = fmaf(ea, bfu_hi(hv.y), acc[3]);
                acc[4] = fmaf(ea, bfu_lo(hv.z), acc[4]);
                acc[5] = fmaf(ea, bfu_hi(hv.z), acc[5]);
                acc[6] = fmaf(ea, bfu_lo(hv.w), acc[6]);
                acc[7] = fmaf(ea, bfu_hi(hv.w), acc[7]);
            }
        }
    }
    #pragma unroll
    for (int o = 32; o; o >>= 1) sm += __shfl_xor(sm, o);
    #pragma unroll
    for (int k = 0; k < 8; ++k) {
        acc[k] += __shfl_xor(acc[k], 8);
        acc[k] += __shfl_xor(acc[k], 16);
        acc[k] += __shfl_xor(acc[k], 32);
    }
    float inv = 1.f / (sm + DEPS);
    int c0 = l8 << 3;
    float4 bA = *(const float4*)&b1l[c0];
    float4 bB = *(const float4*)&b1l[c0 + 4];
    float v0 = fmaxf(fmaf(acc[0], inv, bA.x), 0.f);
    float v1 = fmaxf(fmaf(acc[1], inv, bA.y), 0.f);
    float v2 = fmaxf(fmaf(acc[2], inv, bA.z), 0.f);
    float v3 = fmaxf(fmaf(acc[3], inv, bA.w), 0.f);
    float v4 = fmaxf(fmaf(acc[4], inv, bB.x), 0.f);
    float v5 = fmaxf(fmaf(acc[5], inv, bB.y), 0.f);
    float v6 = fmaxf(fmaf(acc[6], inv, bB.z), 0.f);
    float v7 = fmaxf(fmaf(acc[7], inv, bB.w), 0.f);
    float4 wA0 = *(const float4*)&WxT[g8][c0];
    float4 wA1 = *(const float4*)&WxT[g8][c0 + 4];
    float4 wB0 = *(const float4*)&WxT[g8 + 8][c0];
    float4 wB1 = *(const float4*)&WxT[g8 + 8][c0 + 4];
    float rA = fmaf(v0, wA0.x, fmaf(v1, wA0.y, fmaf(v2, wA0.z, fmaf(v3, wA0.w,
               fmaf(v4, wA1.x, fmaf(v5, wA1.y, fmaf(v6, wA1.z, v7 * wA1.w)))))));
    float rB = fmaf(v0, wB0.x, fmaf(v1, wB0.y, fmaf(v2, wB0.z, fmaf(v3, wB0.w,
               fmaf(v4, wB1.x, fmaf(v5, wB1.y, fmaf(v6, wB1.z, v7 * wB1.w)))))));
    rA += __shfl_xor(rA, 1); rA += __shfl_xor(rA, 2); rA += __shfl_xor(rA, 4);
    rB += __shfl_xor(rB, 1); rB += __shfl_xor(rB, 2); rB += __shfl_xor(rB, 4);
    if (l8 == 0) {
        h2p[(size_t)d * 8 + g8] = rA;            // slots 0..6 = h2, 7 = as2
        if (g8 == 0) ad2[d] = rB;                // output 8 = ad2
    }
}

// fused layer-2 aggregate + bias. 8 lanes per row, 8 rows per wave.
// Self-loop analytic: lane l8==0 adds exp(leaky(as2[d]+ad2[d])) * h2p[d].
__global__ __launch_bounds__(256) void f_agg2(
    const int* __restrict__ cnt, const unsigned* __restrict__ bkt,
    const uint2* __restrict__ ovf, const int* __restrict__ ovfn,
    const float* __restrict__ h2p, const float* __restrict__ ad2,
    const float* __restrict__ b2, float* __restrict__ out, int N)
{
    __shared__ float b2l[7];
    if (threadIdx.x < 7) b2l[threadIdx.x] = b2[threadIdx.x];
    __syncthreads();
    int lane = threadIdx.x & 63;
    int wv = threadIdx.x >> 6;
    int grp = lane >> 3, l8 = lane & 7;
    int d = blockIdx.x * 32 + wv * 8 + grp;
    bool valid = d < N;
    int lenf = 0; float adv = 0.f;
    if (valid) { lenf = cnt[d]; adv = ad2[d]; }
    int nc = min(lenf, CAP);
    size_t r0 = (size_t)d * CAP;
    float sm = 0.f;
    float a0 = 0.f, a1 = 0.f, a2 = 0.f, a3 = 0.f, a4 = 0.f, a5 = 0.f, a6 = 0.f;
    if (valid && l8 == 0) {                      // analytic self-loop term
        const float* hr = &h2p[(size_t)d * 8];
        float4 A = *(const float4*)hr;
        float4 B = *(const float4*)(hr + 4);
        float a = B.w + adv;
        a = (a > 0.f) ? a : 0.2f * a;
        float ea = __expf(a);
        sm += ea;
        a0 = fmaf(ea, A.x, a0); a1 = fmaf(ea, A.y, a1);
        a2 = fmaf(ea, A.z, a2); a3 = fmaf(ea, A.w, a3);
        a4 = fmaf(ea, B.x, a4); a5 = fmaf(ea, B.y, a5);
        a6 = fmaf(ea, B.z, a6);
    }
    for (int p = l8; p < nc; p += 8) {
        unsigned u = bkt[r0 + p];
        int s = (int)(u >> 15);
        const float* hr = &h2p[(size_t)s * 8];
        float4 A = *(const float4*)hr;
        float4 B = *(const float4*)(hr + 4);
        float a = B.w + adv;
        a = (a > 0.f) ? a : 0.2f * a;
        float ea = __expf(a + dec_wt(u));
        sm += ea;
        a0 = fmaf(ea, A.x, a0); a1 = fmaf(ea, A.y, a1);
        a2 = fmaf(ea, A.z, a2); a3 = fmaf(ea, A.w, a3);
        a4 = fmaf(ea, B.x, a4); a5 = fmaf(ea, B.y, a5);
        a6 = fmaf(ea, B.z, a6);
    }
    if (lenf > CAP) {                            // rare overflow path
        int no = min(*ovfn, OVF_MAX);
        for (int i = l8; i < no; i += 8) {
            uint2 ov = ovf[i];
            if ((int)ov.x == d) {
                unsigned u = ov.y;
                int s = (int)(u >> 15);
                const float* hr = &h2p[(size_t)s * 8];
                float4 A = *(const float4*)hr;
                float4 B = *(const float4*)(hr + 4);
                float a = B.w + adv;
                a = (a > 0.f) ? a : 0.2f * a;
                float ea = __expf(a + dec_wt(u));
                sm += ea;
                a0 = fmaf(ea, A.x, a0); a1 = fmaf(ea, A.y, a1);
                a2 = fmaf(ea, A.z, a2); a3 = fmaf(ea, A.w, a3);
                a4 = fmaf(ea, B.x, a4); a5 = fmaf(ea, B.y, a5);
                a6 = fmaf(ea, B.z, a6);
            }
        }
    }
    #pragma unroll
    for (int o = 4; o; o >>= 1) {
        sm += __shfl_xor(sm, o);
        a0 += __shfl_xor(a0, o); a1 += __shfl_xor(a1, o);
        a2 += __shfl_xor(a2, o); a3 += __shfl_xor(a3, o);
        a4 += __shfl_xor(a4, o); a5 += __shfl_xor(a5, o);
        a6 += __shfl_xor(a6, o);
    }
    if (valid && l8 < 7) {
        float inv = 1.f / (sm + DEPS);
        float val = (l8 < 4) ? ((l8 < 2) ? (l8 ? a1 : a0) : ((l8 == 2) ? a2 : a3))
                             : ((l8 < 6) ? ((l8 == 4) ? a4 : a5) : a6);
        out[(size_t)d * 7 + l8] = fmaf(val, inv, b2l[l8]);
    }
}

// ============================== HOST ======================================

extern "C" void kernel_launch(void* const* d_in, const int* in_sizes, int n_in,
                              void* d_out, int out_size, void* d_ws, size_t ws_size,
                              hipStream_t stream) {
    const float* x   = (const float*)d_in[0];
    const int*   ei  = (const int*)d_in[1];
    const float* ew  = (const float*)d_in[2];
    const float* W1  = (const float*)d_in[3];
    const float* as1 = (const float*)d_in[4];
    const float* ad1 = (const float*)d_in[5];
    const float* b1  = (const float*)d_in[6];
    const float* W2  = (const float*)d_in[7];
    const float* a2s = (const float*)d_in[8];
    const float* a2d = (const float*)d_in[9];
    const float* b2  = (const float*)d_in[10];

    int N = in_sizes[0] / 128;
    int E = in_sizes[1] / 2;
    const int* srcv = ei;
    const int* dstv = ei + E;
    float* out = (float*)d_out;

    // workspace (256B aligned): ~31.45 MB (dense cnt -- R8 proved padding hurts).
    size_t A = 0;
    auto take = [&](size_t b) { size_t o = A; A = (A + b + 255) & ~(size_t)255; return o; };
    size_t o_h1   = take((size_t)N * 64 * 2);       // 12.8 MB
    size_t o_bkt  = take((size_t)N * CAP * 4);      // 12.8 MB
    size_t o_h2p  = take((size_t)N * 8 * 4);        //  3.2 MB padded (+as2)
    size_t o_ovf  = take((size_t)OVF_MAX * 8);      //  1.0 MB
    size_t o_cnt  = take((size_t)N * 4);            //  0.4 MB
    size_t o_ovfn = take(256);                      //  (contiguous after cnt)
    size_t o_asrc = take((size_t)N * 4);
    size_t o_adst = take((size_t)N * 4);
    size_t o_ad2  = take((size_t)N * 4);

    char* base = (char*)d_ws;
    bf16*     h1    = (bf16*)(base + o_h1);
    unsigned* bkt   = (unsigned*)(base + o_bkt);
    float*    h2p   = (float*)(base + o_h2p);
    uint2*    ovf   = (uint2*)(base + o_ovf);
    int*      cnt   = (int*)(base + o_cnt);
    int*      ovfn  = (int*)(base + o_ovfn);
    float*    asrc  = (float*)(base + o_asrc);
    float*    adst  = (float*)(base + o_adst);
    float*    ad2   = (float*)(base + o_ad2);

    int gG = (N + 31) / 32;                  // gemm-role blocks (~3125)
    int gH = (E + 2047) / 2048;              // fused hist+scat blocks (~782, real edges only)
    int chunks = max((gG + 14) / 15, (gH + 3) / 4);
    int gridGH = chunks * 19;                // 15:4 stripe for co-residency

    hipMemsetAsync(cnt, 0, (size_t)N * 4 + 256, stream);   // cnt + ovfn
    f_gemm_hs<<<gridGH, 256, 0, stream>>>(x, W1, as1, ad1, h1, asrc, adst,
                                          srcv, dstv, ew, cnt, bkt, ovf, ovfn,
                                          N, E, gG, gH);
    f_agg1 <<<(N + 3) / 4, 256, 0, stream>>>(cnt, bkt, ovf, ovfn, asrc, adst, h1,
                                             b1, W2, a2s, a2d, h2p, ad2, N);
    f_agg2 <<<(N + 31) / 32, 256, 0, stream>>>(cnt, bkt, ovf, ovfn, h2p, ad2, b2, out, N);
}